// Round 7
// baseline (3461.033 us; speedup 1.0000x reference)
//
#include <hip/hip_runtime.h>

// Neural SDE rollout -- all-gather, quarter-K blocks, no atomic-RMW reduce.
// 64 groups x 16 rows x 8 blocks. Block j of a group owns (Kq=j&3, nh=j>>2):
//   - computes h_mu and h_sg ONLY for H-cols [Kq*128, Kq*128+128)
//   - GEMM2 partials over that K-quarter for output cols [nh*32, nh*32+32)
//   - drift cols == diffusion cols for this block -> ONE partial buffer
//     per (slot, Kq): exchange = plain device-scope stores + 1 counter
//     RMW per block per step (MALL RMW wall from R3-R5 avoided).
// y kept in registers (thread-owned); LDS 29,184 B <= 32 KB with
// launch_bounds(512,4) -> 2 blocks/CU (R4-proven recipe, 48% occupancy),
// decoupled groups hide each other's sync/L2 latency.
// Split-fp16 numerics (hi+lo, 3 MFMAs) -- absmax 2.0 across R2-R6.

typedef _Float16 f16x8 __attribute__((ext_vector_type(8)));
typedef float    f32x4 __attribute__((ext_vector_type(4)));

#define MFMA(a,b,c) __builtin_amdgcn_mfma_f32_16x16x32_f16(a,b,c,0,0,0)

#define Bb 1024
#define Tt 128
#define NG 64          // groups (16 batch rows each)
#define GB 8           // blocks per group
#define Rr 16          // rows per group (one MFMA M-tile)
#define NT 512         // threads per block (8 waves)

// packed fragment regions in d_ws (units: halves) -- identical pack since R2
#define W2SG_OFF 0
#define W2SG_HALVES (64*16*2*512)
#define W2MU_OFF (W2SG_OFF + W2SG_HALVES)
#define W2MU_HALVES (4*16*2*512)
#define W1MU_OFF (W2MU_OFF + W2MU_HALVES)
#define W1_HALVES (32*3*2*512)
#define W1SG_OFF (W1MU_OFF + W1_HALVES)
#define WS_HALVES (W1SG_OFF + W1_HALVES)

// partial buffers: [slot(2)][Kq(4)][g(64)][1024 floats]
#define PART_OFF ((size_t)WS_HALVES * 2)
#define PART_FLOATS (2*4*NG*1024)
#define CNT_OFF  (PART_OFF + (size_t)PART_FLOATS*4)
#define CNT_STRIDE 16                 // pad counters to 64 B

__global__ __launch_bounds__(256) void pack_weights(
    const float* __restrict__ W1_mu, const float* __restrict__ W2_mu,
    const float* __restrict__ W1_sg, const float* __restrict__ W2_sg,
    _Float16* __restrict__ wsh)
{
    int gid = blockIdx.x * 256 + threadIdx.x;
    if (gid >= 81920) return;
    const float* src; int ncols, kvalid; size_t dst;
    int id, tile, ks, lane;
    if (gid < 65536) {                 // W2_sg: 64 tiles x 16 ks x 64 lanes
        id = gid; tile = id >> 10; id &= 1023; ks = id >> 6; lane = id & 63;
        src = W2_sg; ncols = 1024; kvalid = 512;
        dst = W2SG_OFF + (size_t)((tile*16 + ks)*2) * 512 + lane*8;
    } else if (gid < 69632) {          // W2_mu: 4 x 16 x 64
        id = gid - 65536; tile = id >> 10; id &= 1023; ks = id >> 6; lane = id & 63;
        src = W2_mu; ncols = 64; kvalid = 512;
        dst = W2MU_OFF + (size_t)((tile*16 + ks)*2) * 512 + lane*8;
    } else if (gid < 75776) {          // W1_mu: 32 tiles x 3 ks x 64
        id = gid - 69632; tile = id / 192; id %= 192; ks = id >> 6; lane = id & 63;
        src = W1_mu; ncols = 512; kvalid = 80;
        dst = W1MU_OFF + (size_t)((tile*3 + ks)*2) * 512 + lane*8;
    } else {                           // W1_sg
        id = gid - 75776; tile = id / 192; id %= 192; ks = id >> 6; lane = id & 63;
        src = W1_sg; ncols = 512; kvalid = 80;
        dst = W1SG_OFF + (size_t)((tile*3 + ks)*2) * 512 + lane*8;
    }
    const int n  = tile*16 + (lane & 15);
    const int kb = ks*32 + ((lane >> 4) << 3);
    f16x8 hi8, lo8;
    #pragma unroll
    for (int jj = 0; jj < 8; ++jj) {
        int k = kb + jj;
        float wv = (k < kvalid) ? src[(size_t)k * ncols + n] : 0.f;
        _Float16 h = (_Float16)wv;
        hi8[jj] = h;
        lo8[jj] = (_Float16)(wv - (float)h);
    }
    *((f16x8*)(wsh + dst))       = hi8;
    *((f16x8*)(wsh + dst + 512)) = lo8;
}

__global__ __launch_bounds__(NT, 4) void nsde_qk(
    const float* __restrict__ y0, const float* __restrict__ controls,
    const float* __restrict__ noise,
    const float* __restrict__ b1_mu, const float* __restrict__ b2_mu,
    const float* __restrict__ b1_sg, const float* __restrict__ b2_sg,
    const _Float16* __restrict__ wf,
    float* __restrict__ part, unsigned int* __restrict__ cnt,
    float* __restrict__ out)
{
    __shared__ _Float16 s_xhi[Rr][104], s_xlo[Rr][104];   // 6656 B
    __shared__ _Float16 s_mhi[Rr][136], s_mlo[Rr][136];   // h_mu quarter, 8704 B
    __shared__ _Float16 s_shi[Rr][136], s_slo[Rr][136];   // h_sg quarter, 8704 B
    __shared__ float s_dw[Rr][16];                        // 1024 B
    __shared__ float s_pd[Rr][32];                        // drift partial, 2048 B
    __shared__ float s_ps[Rr][32];                        // diff partial,  2048 B
    // total 29,184 B

    const int tid  = threadIdx.x;
    const int lane = tid & 63, w = tid >> 6;
    const int m15  = lane & 15, quad = lane >> 4;
    const int j    = blockIdx.x & 7;    // (Kq, nh)
    const int g    = blockIdx.x >> 3;
    const int Kq   = j & 3;
    const int nh   = j >> 2;
    const int r0   = g * Rr;

    // per-wave constants
    const int tmu = Kq*8 + w;                        // W1_mu H-tile (GEMM1)
    const int tsg = Kq*8 + w;                        // W1_sg H-tile (GEMM1)
    const float b1m = b1_mu[tmu*16 + m15];
    const float b1s = b1_sg[tsg*16 + m15];
    float b2s[4];
    #pragma unroll
    for (int t = 0; t < 4; ++t)
        b2s[t] = b2_sg[(nh*32 + w*4 + t)*16 + m15];  // full bias (folded once
                                                     // per n: only in dW-fold
                                                     // product; see below)
    // bias policy: b2_sg/b2_mu added only by Kq==0 blocks
    #pragma unroll
    for (int t = 0; t < 4; ++t) if (Kq != 0) b2s[t] = 0.f;
    const int ntmu = nh*2 + w;                       // waves 0,1: drift n-tile
    const float b2m = (w < 2 && Kq == 0) ? b2_mu[ntmu*16 + m15]*0.01f : 0.f;

    // ---- init
    for (int e = tid; e < Rr*24; e += NT) {          // zero x K-pad cols
        int r = e / 24, c = 80 + e % 24;
        s_xhi[r][c] = (_Float16)0.f; s_xlo[r][c] = (_Float16)0.f;
    }
    // y in registers: thread owns elements e0=tid*2, e0+1  (r=e0>>6, n=e0&63)
    const int e0 = tid*2, yr = e0 >> 6, yn = e0 & 63;
    float ya, yb;
    {
        float2 yv = *(const float2*)&y0[(size_t)(r0 + yr)*64 + yn];
        ya = yv.x; yb = yv.y;
        _Float16 h0 = (_Float16)ya, h1 = (_Float16)yb;
        s_xhi[yr][yn] = h0;   s_xlo[yr][yn]   = (_Float16)(ya - (float)h0);
        s_xhi[yr][yn+1] = h1; s_xlo[yr][yn+1] = (_Float16)(yb - (float)h1);
        if ((tid >> 6) == j)
            *(float2*)&out[(size_t)(r0 + yr)*64 + yn] = yv;
    }
    if (tid < 256) {
        int r = tid >> 4, c = tid & 15;
        float u = controls[c];
        _Float16 h = (_Float16)u;
        s_xhi[r][64+c] = h; s_xlo[r][64+c] = (_Float16)(u - (float)h);
        s_dw[r][c] = noise[(size_t)(r0 + r)*16 + c] * 0.1f;
    }
    __syncthreads();

    for (int k = 0; k < Tt-1; ++k) {
        // ======== phase 1: GEMM1 quarter -- each wave: 1 mu tile + 1 sg tile
        {
            f16x8 xah[3], xal[3];
            #pragma unroll
            for (int ks = 0; ks < 3; ++ks) {
                xah[ks] = *(const f16x8*)&s_xhi[m15][ks*32 + quad*8];
                xal[ks] = *(const f16x8*)&s_xlo[m15][ks*32 + quad*8];
            }
            f32x4 m0 = {0,0,0,0}, m1 = {0,0,0,0}, m2 = {0,0,0,0};
            f32x4 s0 = {0,0,0,0}, s1 = {0,0,0,0}, s2 = {0,0,0,0};
            #pragma unroll
            for (int ks = 0; ks < 3; ++ks) {
                const _Float16* bpm = wf + W1MU_OFF + (size_t)((tmu*3+ks)*2)*512 + lane*8;
                const _Float16* bps = wf + W1SG_OFF + (size_t)((tsg*3+ks)*2)*512 + lane*8;
                f16x8 bmh = *(const f16x8*)bpm;
                f16x8 bml = *(const f16x8*)(bpm + 512);
                f16x8 bsh = *(const f16x8*)bps;
                f16x8 bsl = *(const f16x8*)(bps + 512);
                m0 = MFMA(xah[ks], bmh, m0);
                m1 = MFMA(xah[ks], bml, m1);
                m2 = MFMA(xal[ks], bmh, m2);
                s0 = MFMA(xah[ks], bsh, s0);
                s1 = MFMA(xah[ks], bsl, s1);
                s2 = MFMA(xal[ks], bsh, s2);
            }
            f32x4 sm = m0 + m1 + m2, ss = s0 + s1 + s2;
            #pragma unroll
            for (int rg = 0; rg < 4; ++rg) {
                int row = quad*4 + rg;
                float vm = fmaxf(sm[rg] + b1m, 0.f);
                _Float16 hm = (_Float16)vm;
                s_mhi[row][w*16+m15] = hm;
                s_mlo[row][w*16+m15] = (_Float16)(vm - (float)hm);
                float vs = fmaxf(ss[rg] + b1s, 0.f);
                _Float16 hs = (_Float16)vs;
                s_shi[row][w*16+m15] = hs;
                s_slo[row][w*16+m15] = (_Float16)(vs - (float)hs);
            }
        }
        __syncthreads();

        // ======== phase 2: GEMM2 over this K-quarter
        float dwv[4];
        #pragma unroll
        for (int rg = 0; rg < 4; ++rg)
            dwv[rg] = s_dw[quad*4 + rg][m15];

        // -- drift partial (waves 0,1): n-tile ntmu, writes s_pd fully
        if (w < 2) {
            f32x4 hh = {0,0,0,0}, hl = {0,0,0,0}, lh = {0,0,0,0};
            #pragma unroll
            for (int ksl = 0; ksl < 4; ++ksl) {
                const int ks = Kq*4 + ksl;
                const _Float16* bp = wf + W2MU_OFF + (size_t)((ntmu*16+ks)*2)*512 + lane*8;
                f16x8 bh = *(const f16x8*)bp;
                f16x8 bl = *(const f16x8*)(bp + 512);
                f16x8 ah = *(const f16x8*)&s_mhi[m15][ksl*32 + quad*8];
                f16x8 al = *(const f16x8*)&s_mlo[m15][ksl*32 + quad*8];
                hh = MFMA(ah, bh, hh); hl = MFMA(ah, bl, hl); lh = MFMA(al, bh, lh);
            }
            f32x4 s = hh + hl + lh;
            #pragma unroll
            for (int rg = 0; rg < 4; ++rg)
                s_pd[quad*4 + rg][w*16 + m15] = s[rg]*0.01f + b2m;
        }

        // -- diffusion partials: 4 n-tiles per wave, fold dW, write s_ps
        {
            f16x8 ah[4], al[4];
            #pragma unroll
            for (int ksl = 0; ksl < 4; ++ksl) {
                ah[ksl] = *(const f16x8*)&s_shi[m15][ksl*32 + quad*8];
                al[ksl] = *(const f16x8*)&s_slo[m15][ksl*32 + quad*8];
            }
            #pragma unroll 2
            for (int t = 0; t < 4; ++t) {
                const int nt = nh*32 + w*4 + t;
                f32x4 hh = {0,0,0,0}, hl = {0,0,0,0}, lh = {0,0,0,0};
                #pragma unroll
                for (int ksl = 0; ksl < 4; ++ksl) {
                    const int ks = Kq*4 + ksl;
                    const _Float16* bp = wf + W2SG_OFF + (size_t)((nt*16+ks)*2)*512 + lane*8;
                    f16x8 bh = *(const f16x8*)bp;
                    f16x8 bl = *(const f16x8*)(bp + 512);
                    hh = MFMA(ah[ksl], bh, hh);
                    hl = MFMA(ah[ksl], bl, hl);
                    lh = MFMA(al[ksl], bh, lh);
                }
                f32x4 s = hh + hl + lh;
                #pragma unroll
                for (int rg = 0; rg < 4; ++rg) {
                    float v = (s[rg] + b2s[t]) * dwv[rg];
                    v += __shfl_xor(v, 1); v += __shfl_xor(v, 2);
                    v += __shfl_xor(v, 4); v += __shfl_xor(v, 8);
                    if (m15 == 0) s_ps[quad*4 + rg][w*4 + t] = v;
                }
            }
        }
        __syncthreads();

        // ======== phase 3: store partial, release, spin
        const int slot = k & 1;
        float* pb = part + ((size_t)(slot*4 + Kq)*NG + g)*1024;
        {
            const int row = tid >> 5, lc = tid & 31;
            float v = s_pd[row][lc] + s_ps[row][lc];
            __hip_atomic_store(&pb[row*64 + nh*32 + lc], v,
                               __ATOMIC_RELAXED, __HIP_MEMORY_SCOPE_AGENT);
        }
        __syncthreads();   // drains vmcnt: stores complete before release
        if (tid == 0) {
            __hip_atomic_fetch_add(&cnt[g*CNT_STRIDE], 1u, __ATOMIC_RELEASE,
                                   __HIP_MEMORY_SCOPE_AGENT);
            while (__hip_atomic_load(&cnt[g*CNT_STRIDE], __ATOMIC_RELAXED,
                                     __HIP_MEMORY_SCOPE_AGENT) < (unsigned)GB*(k+1))
                __builtin_amdgcn_s_sleep(2);
        }
        __syncthreads();

        // ======== phase 4: gather 4 quarters, y update, out, next x/dW
        {
            float sa = 0.f, sb = 0.f;
            const float* base = part + (size_t)slot*4*NG*1024 + (size_t)g*1024;
            #pragma unroll
            for (int q = 0; q < 4; ++q) {
                sa += __hip_atomic_load(base + (size_t)q*NG*1024 + e0,
                                        __ATOMIC_RELAXED, __HIP_MEMORY_SCOPE_AGENT);
                sb += __hip_atomic_load(base + (size_t)q*NG*1024 + e0 + 1,
                                        __ATOMIC_RELAXED, __HIP_MEMORY_SCOPE_AGENT);
            }
            ya += sa; yb += sb;
            _Float16 h0 = (_Float16)ya, h1 = (_Float16)yb;
            s_xhi[yr][yn] = h0;   s_xlo[yr][yn]   = (_Float16)(ya - (float)h0);
            s_xhi[yr][yn+1] = h1; s_xlo[yr][yn+1] = (_Float16)(yb - (float)h1);
            if ((tid >> 6) == j) {
                float2 o = {ya, yb};
                *(float2*)&out[((size_t)(k+1)*Bb + r0 + yr)*64 + yn] = o;
            }
        }
        if (k < Tt-2 && tid < 256) {
            int r = tid >> 4, c = tid & 15;
            float u = controls[(size_t)(k+1)*16 + c];
            _Float16 h = (_Float16)u;
            s_xhi[r][64+c] = h; s_xlo[r][64+c] = (_Float16)(u - (float)h);
            s_dw[r][c] = noise[((size_t)(k+1)*Bb + r0 + r)*16 + c] * 0.1f;
        }
        __syncthreads();
    }
}

extern "C" void kernel_launch(void* const* d_in, const int* in_sizes, int n_in,
                              void* d_out, int out_size, void* d_ws, size_t ws_size,
                              hipStream_t stream) {
    const float* y0       = (const float*)d_in[0];
    const float* controls = (const float*)d_in[1];
    const float* noise    = (const float*)d_in[2];
    const float* W1_mu    = (const float*)d_in[3];
    const float* b1_mu    = (const float*)d_in[4];
    const float* W2_mu    = (const float*)d_in[5];
    const float* b2_mu    = (const float*)d_in[6];
    const float* W1_sg    = (const float*)d_in[7];
    const float* b1_sg    = (const float*)d_in[8];
    const float* W2_sg    = (const float*)d_in[9];
    const float* b2_sg    = (const float*)d_in[10];
    float* out = (float*)d_out;
    _Float16* wsh = (_Float16*)d_ws;
    float* part = (float*)((char*)d_ws + PART_OFF);
    unsigned int* cnt = (unsigned int*)((char*)d_ws + CNT_OFF);

    // zero only the counters (partial buffers fully overwritten each step)
    hipMemsetAsync((char*)d_ws + CNT_OFF, 0, (size_t)NG*CNT_STRIDE*4, stream);
    pack_weights<<<320, 256, 0, stream>>>(W1_mu, W2_mu, W1_sg, W2_sg, wsh);
    nsde_qk<<<NG*GB, NT, 0, stream>>>(y0, controls, noise,
                                      b1_mu, b2_mu, b1_sg, b2_sg,
                                      (const _Float16*)wsh,
                                      part, cnt, out);
}

// Round 8
// 2459.605 us; speedup vs baseline: 1.4072x; 1.4072x over previous
//
#include <hip/hip_runtime.h>

// Neural SDE rollout = R4 structure (best: 2294 us) + weights RESIDENT IN
// REGISTERS. R4's K-loop re-read ~320 KB of B-fragments from L2 every step
// (4.4 us/CU load-pipe at 144 GB/s/CU). The per-wave fragment working set is
// only ~168 VGPRs; CDNA4's 2048-VGPR/SIMD pool at launch_bounds(512,2)
// holds it permanently -> zero weight loads inside the time loop.
// Exchange unchanged from R4 (atomicAdd partials + release counter + 2-load
// gather; relaxed atomics, no acquire fences): absmax 2.0 across R2-R7.
// 64 groups x 16 rows x 8 blocks = 512 blocks, LDS 29 KB -> 2 blocks/CU.

typedef _Float16 f16x8 __attribute__((ext_vector_type(8)));
typedef float    f32x4 __attribute__((ext_vector_type(4)));

#define MFMA(a,b,c) __builtin_amdgcn_mfma_f32_16x16x32_f16(a,b,c,0,0,0)

#define Bb 1024
#define Tt 128
#define NG 64          // groups
#define GB 8           // blocks per group (split-K over H=512 -> 64 cols each)
#define Rr 16          // rows per group (one MFMA M-tile)
#define NT 512         // threads per block (8 waves)

// packed fragment regions in d_ws (units: halves) -- identical pack since R2
#define W2SG_OFF 0
#define W2SG_HALVES (64*16*2*512)
#define W2MU_OFF (W2SG_OFF + W2SG_HALVES)
#define W2MU_HALVES (4*16*2*512)
#define W1MU_OFF (W2MU_OFF + W2MU_HALVES)
#define W1_HALVES (32*3*2*512)
#define W1SG_OFF (W1MU_OFF + W1_HALVES)
#define WS_HALVES (W1SG_OFF + W1_HALVES)
#define ACC_BYTES_OFF ((size_t)WS_HALVES * 2)
#define ACC_FLOATS (3 * NG * 1024)        // 3 slots x 64 groups x 16x64
#define CNT_BYTES_OFF (ACC_BYTES_OFF + (size_t)ACC_FLOATS * 4)
#define CNT_STRIDE 16                     // pad counters to 64 B

__global__ __launch_bounds__(256) void pack_weights(
    const float* __restrict__ W1_mu, const float* __restrict__ W2_mu,
    const float* __restrict__ W1_sg, const float* __restrict__ W2_sg,
    _Float16* __restrict__ wsh)
{
    int gid = blockIdx.x * 256 + threadIdx.x;
    if (gid >= 81920) return;
    const float* src; int ncols, kvalid; size_t dst;
    int id, tile, ks, lane;
    if (gid < 65536) {                 // W2_sg: 64 tiles x 16 ks x 64 lanes
        id = gid; tile = id >> 10; id &= 1023; ks = id >> 6; lane = id & 63;
        src = W2_sg; ncols = 1024; kvalid = 512;
        dst = W2SG_OFF + (size_t)((tile*16 + ks)*2) * 512 + lane*8;
    } else if (gid < 69632) {          // W2_mu: 4 x 16 x 64
        id = gid - 65536; tile = id >> 10; id &= 1023; ks = id >> 6; lane = id & 63;
        src = W2_mu; ncols = 64; kvalid = 512;
        dst = W2MU_OFF + (size_t)((tile*16 + ks)*2) * 512 + lane*8;
    } else if (gid < 75776) {          // W1_mu: 32 tiles x 3 ks x 64
        id = gid - 69632; tile = id / 192; id %= 192; ks = id >> 6; lane = id & 63;
        src = W1_mu; ncols = 512; kvalid = 80;
        dst = W1MU_OFF + (size_t)((tile*3 + ks)*2) * 512 + lane*8;
    } else {                           // W1_sg
        id = gid - 75776; tile = id / 192; id %= 192; ks = id >> 6; lane = id & 63;
        src = W1_sg; ncols = 512; kvalid = 80;
        dst = W1SG_OFF + (size_t)((tile*3 + ks)*2) * 512 + lane*8;
    }
    const int n  = tile*16 + (lane & 15);
    const int kb = ks*32 + ((lane >> 4) << 3);
    f16x8 hi8, lo8;
    #pragma unroll
    for (int jj = 0; jj < 8; ++jj) {
        int k = kb + jj;
        float wv = (k < kvalid) ? src[(size_t)k * ncols + n] : 0.f;
        _Float16 h = (_Float16)wv;
        hi8[jj] = h;
        lo8[jj] = (_Float16)(wv - (float)h);
    }
    *((f16x8*)(wsh + dst))       = hi8;
    *((f16x8*)(wsh + dst + 512)) = lo8;
}

__global__ __launch_bounds__(NT, 2) void nsde_regw(
    const float* __restrict__ y0, const float* __restrict__ controls,
    const float* __restrict__ noise,
    const float* __restrict__ b1_mu, const float* __restrict__ b2_mu,
    const float* __restrict__ b1_sg, const float* __restrict__ b2_sg,
    const _Float16* __restrict__ wf,
    float* __restrict__ accbuf, unsigned int* __restrict__ cnt,
    float* __restrict__ out)
{
    __shared__ _Float16 s_xhi[Rr][104], s_xlo[Rr][104];     // x, K=96 (+pad)
    __shared__ _Float16 s_hhi[2][Rr][72], s_hlo[2][Rr][72]; // h slices (64+pad)
    __shared__ float s_y[Rr*64];
    __shared__ float s_dw[Rr][16];
    __shared__ float s_part[Rr*64];  // sg partial (dW-folded)
    __shared__ float s_pmu[Rr*64];   // mu partial (*dt)

    const int tid  = threadIdx.x;
    const int lane = tid & 63, w = tid >> 6;
    const int m15  = lane & 15, quad = lane >> 4;
    const int j    = blockIdx.x & 7;        // K-slice id
    const int g    = blockIdx.x >> 3;       // group
    const int r0   = g * Rr;

    // per-wave constants
    const int l  = w >> 2;                  // GEMM1 layer: 0=mu 1=sg
    const int ct = w & 3;                   // GEMM1 col-tile within slice
    const int tg = j*4 + ct;                // global W1 H-tile
    const _Float16* w1base = wf + (l ? W1SG_OFF : W1MU_OFF);
    const float bias1 = (l ? b1_sg : b1_mu)[j*64 + ct*16 + m15];
    float b2v[8];
    #pragma unroll
    for (int t = 0; t < 8; ++t)
        b2v[t] = (j == 0) ? b2_sg[(w + t*8)*16 + m15] : 0.f;
    const float b2m = (w < 4 && j == 0) ? b2_mu[w*16 + m15] * 0.01f : 0.f;

    // ======== LOAD ALL WEIGHT FRAGMENTS INTO REGISTERS (once, pre-loop) ====
    // GEMM1: this wave's W1 tile, 3 K-steps x (hi,lo)  -> 24 VGPRs
    f16x8 w1h[3], w1l[3];
    #pragma unroll
    for (int ks = 0; ks < 3; ++ks) {
        const _Float16* bp = w1base + (size_t)((tg*3 + ks)*2)*512 + lane*8;
        w1h[ks] = *(const f16x8*)bp;
        w1l[ks] = *(const f16x8*)(bp + 512);
    }
    // GEMM2 mu (waves 0..3): 2 K-steps x (hi,lo) -> 16 VGPRs
    f16x8 wmh[2], wml[2];
    if (w < 4) {
        const _Float16* bp = wf + W2MU_OFF + (size_t)((w*16 + 2*j)*2)*512 + lane*8;
        wmh[0] = *(const f16x8*)(bp);
        wml[0] = *(const f16x8*)(bp + 512);
        wmh[1] = *(const f16x8*)(bp + 1024);
        wml[1] = *(const f16x8*)(bp + 1536);
    }
    // GEMM2 sg: 8 n-tiles x 2 K-steps x (hi,lo) -> 128 VGPRs
    f16x8 wsh0[8], wsl0[8], wsh1[8], wsl1[8];
    #pragma unroll
    for (int t = 0; t < 8; ++t) {
        const int nt = w + t*8;
        const _Float16* bp = wf + W2SG_OFF + (size_t)((nt*16 + 2*j)*2)*512 + lane*8;
        wsh0[t] = *(const f16x8*)(bp);
        wsl0[t] = *(const f16x8*)(bp + 512);
        wsh1[t] = *(const f16x8*)(bp + 1024);
        wsl1[t] = *(const f16x8*)(bp + 1536);
    }

    // ---- init
    for (int e = tid; e < Rr*24; e += NT) {   // zero x K-pad cols 80..103
        int r = e / 24, c = 80 + e % 24;
        s_xhi[r][c] = (_Float16)0.f; s_xlo[r][c] = (_Float16)0.f;
    }
    if (tid < 256) {
        int e0i = tid*4, r = e0i >> 6, n = e0i & 63;
        float4 yv = *(const float4*)&y0[(size_t)(r0 + r)*64 + n];
        float vv[4] = {yv.x, yv.y, yv.z, yv.w};
        #pragma unroll
        for (int q = 0; q < 4; ++q) {
            s_y[e0i+q] = vv[q];
            _Float16 h = (_Float16)vv[q];
            s_xhi[r][n+q] = h; s_xlo[r][n+q] = (_Float16)(vv[q] - (float)h);
        }
        if ((tid >> 5) == j)
            *(float4*)&out[(size_t)(r0 + r)*64 + n] = yv;
        int rr2 = tid >> 4, cc2 = tid & 15;
        float u = controls[cc2];
        _Float16 h = (_Float16)u;
        s_xhi[rr2][64+cc2] = h; s_xlo[rr2][64+cc2] = (_Float16)(u - (float)h);
        s_dw[rr2][cc2] = noise[(size_t)(r0 + rr2)*16 + cc2] * 0.1f;
    }
    __syncthreads();

    for (int k = 0; k < Tt-1; ++k) {
        // ======== GEMM1: one 16-col tile per wave (weights in regs)
        {
            f32x4 a0 = {0,0,0,0}, a1 = {0,0,0,0}, a2 = {0,0,0,0};
            #pragma unroll
            for (int ks = 0; ks < 3; ++ks) {
                f16x8 ah = *(const f16x8*)&s_xhi[m15][ks*32 + quad*8];
                f16x8 al = *(const f16x8*)&s_xlo[m15][ks*32 + quad*8];
                a0 = MFMA(ah, w1h[ks], a0);
                a1 = MFMA(ah, w1l[ks], a1);
                a2 = MFMA(al, w1h[ks], a2);
            }
            f32x4 s = a0 + a1 + a2;
            #pragma unroll
            for (int rg = 0; rg < 4; ++rg) {
                int row = quad*4 + rg;
                float v = fmaxf(s[rg] + bias1, 0.f);
                _Float16 h = (_Float16)v;
                s_hhi[l][row][ct*16 + m15] = h;
                s_hlo[l][row][ct*16 + m15] = (_Float16)(v - (float)h);
            }
        }
        __syncthreads();

        // ======== GEMM2 over this block's 64-col K-slice (weights in regs)
        float dwv[4];
        #pragma unroll
        for (int rg = 0; rg < 4; ++rg)
            dwv[rg] = s_dw[quad*4 + rg][m15];

        // -- mu partial (waves 0..3, n-tile = w)
        if (w < 4) {
            f16x8 Mh0 = *(const f16x8*)&s_hhi[0][m15][quad*8];
            f16x8 Ml0 = *(const f16x8*)&s_hlo[0][m15][quad*8];
            f16x8 Mh1 = *(const f16x8*)&s_hhi[0][m15][32 + quad*8];
            f16x8 Ml1 = *(const f16x8*)&s_hlo[0][m15][32 + quad*8];
            f32x4 hh = {0,0,0,0}, hl = {0,0,0,0}, lh = {0,0,0,0};
            hh = MFMA(Mh0, wmh[0], hh); hl = MFMA(Mh0, wml[0], hl); lh = MFMA(Ml0, wmh[0], lh);
            hh = MFMA(Mh1, wmh[1], hh); hl = MFMA(Mh1, wml[1], hl); lh = MFMA(Ml1, wmh[1], lh);
            f32x4 s = hh + hl + lh;
            #pragma unroll
            for (int rg = 0; rg < 4; ++rg)
                s_pmu[(quad*4 + rg)*64 + w*16 + m15] = s[rg]*0.01f + b2m;
        }

        // -- sg partials: 8 n-tiles per wave (all B-frags in regs)
        f16x8 Ah0 = *(const f16x8*)&s_hhi[1][m15][quad*8];
        f16x8 Al0 = *(const f16x8*)&s_hlo[1][m15][quad*8];
        f16x8 Ah1 = *(const f16x8*)&s_hhi[1][m15][32 + quad*8];
        f16x8 Al1 = *(const f16x8*)&s_hlo[1][m15][32 + quad*8];
        #pragma unroll
        for (int t = 0; t < 8; ++t) {
            const int nt = w + t*8;
            f32x4 hh = {0,0,0,0}, hl = {0,0,0,0}, lh = {0,0,0,0};
            hh = MFMA(Ah0, wsh0[t], hh); hl = MFMA(Ah0, wsl0[t], hl); lh = MFMA(Al0, wsh0[t], lh);
            hh = MFMA(Ah1, wsh1[t], hh); hl = MFMA(Ah1, wsl1[t], hl); lh = MFMA(Al1, wsh1[t], lh);
            f32x4 s = hh + hl + lh;
            #pragma unroll
            for (int rg = 0; rg < 4; ++rg) {
                float v = (s[rg] + b2v[t]) * dwv[rg];
                v += __shfl_xor(v, 1); v += __shfl_xor(v, 2);
                v += __shfl_xor(v, 4); v += __shfl_xor(v, 8);
                if (m15 == 0) s_part[(quad*4 + rg)*64 + nt] = v;
            }
        }
        __syncthreads();

        // ======== exchange: atomicAdd partials into slot k%3 (R4 protocol)
        const int slot = k % 3;
        float* ab = accbuf + ((size_t)slot*NG + g)*1024;
        const int e0 = tid*2;
        {
            float v0 = s_part[e0]   + s_pmu[e0];
            float v1 = s_part[e0+1] + s_pmu[e0+1];
            __hip_atomic_fetch_add(&ab[e0],   v0, __ATOMIC_RELAXED,
                                   __HIP_MEMORY_SCOPE_AGENT);
            __hip_atomic_fetch_add(&ab[e0+1], v1, __ATOMIC_RELAXED,
                                   __HIP_MEMORY_SCOPE_AGENT);
        }
        __syncthreads();   // drains vmcnt: all adds complete
        if (tid == 0) {
            __hip_atomic_fetch_add(&cnt[g*CNT_STRIDE], 1u, __ATOMIC_RELEASE,
                                   __HIP_MEMORY_SCOPE_AGENT);
            while (__hip_atomic_load(&cnt[g*CNT_STRIDE], __ATOMIC_RELAXED,
                                     __HIP_MEMORY_SCOPE_AGENT) < (unsigned)GB*(k+1))
                __builtin_amdgcn_s_sleep(2);
        }
        __syncthreads();

        // ======== read sum, y update, out write, next x/dW build
        {
            const int r = e0 >> 6, n = e0 & 63;
            float sum0 = __hip_atomic_load(&ab[e0], __ATOMIC_RELAXED,
                                           __HIP_MEMORY_SCOPE_AGENT);
            float sum1 = __hip_atomic_load(&ab[e0+1], __ATOMIC_RELAXED,
                                           __HIP_MEMORY_SCOPE_AGENT);
            float ya = s_y[e0]   + sum0;
            float yb = s_y[e0+1] + sum1;
            s_y[e0] = ya; s_y[e0+1] = yb;
            _Float16 ha = (_Float16)ya, hb = (_Float16)yb;
            s_xhi[r][n] = ha;   s_xlo[r][n]   = (_Float16)(ya - (float)ha);
            s_xhi[r][n+1] = hb; s_xlo[r][n+1] = (_Float16)(yb - (float)hb);
            if ((tid >> 6) == j) {   // wave j writes this block's 128-elem chunk
                float2 o = {ya, yb};
                *(float2*)&out[((size_t)(k+1)*Bb + r0 + r)*64 + n] = o;
                if (k >= 1) {        // zero slot (k-1)%3 (3-slot rotation safe)
                    float* zb = accbuf + ((size_t)((k-1)%3)*NG + g)*1024;
                    __hip_atomic_store(&zb[e0],   0.f, __ATOMIC_RELAXED,
                                       __HIP_MEMORY_SCOPE_AGENT);
                    __hip_atomic_store(&zb[e0+1], 0.f, __ATOMIC_RELAXED,
                                       __HIP_MEMORY_SCOPE_AGENT);
                }
            }
        }
        if (k < Tt-2 && tid < 256) {
            int r = tid >> 4, c = tid & 15;
            float u = controls[(size_t)(k+1)*16 + c];
            _Float16 h = (_Float16)u;
            s_xhi[r][64+c] = h; s_xlo[r][64+c] = (_Float16)(u - (float)h);
            s_dw[r][c] = noise[((size_t)(k+1)*Bb + r0 + r)*16 + c] * 0.1f;
        }
        __syncthreads();
    }
}

extern "C" void kernel_launch(void* const* d_in, const int* in_sizes, int n_in,
                              void* d_out, int out_size, void* d_ws, size_t ws_size,
                              hipStream_t stream) {
    const float* y0       = (const float*)d_in[0];
    const float* controls = (const float*)d_in[1];
    const float* noise    = (const float*)d_in[2];
    const float* W1_mu    = (const float*)d_in[3];
    const float* b1_mu    = (const float*)d_in[4];
    const float* W2_mu    = (const float*)d_in[5];
    const float* b2_mu    = (const float*)d_in[6];
    const float* W1_sg    = (const float*)d_in[7];
    const float* b1_sg    = (const float*)d_in[8];
    const float* W2_sg    = (const float*)d_in[9];
    const float* b2_sg    = (const float*)d_in[10];
    float* out = (float*)d_out;
    _Float16* wsh = (_Float16*)d_ws;
    float* accbuf = (float*)((char*)d_ws + ACC_BYTES_OFF);
    unsigned int* cnt = (unsigned int*)((char*)d_ws + CNT_BYTES_OFF);

    // zero accumulator slots + padded counters (ws is poisoned 0xAA each call)
    hipMemsetAsync((char*)d_ws + ACC_BYTES_OFF, 0,
                   (size_t)ACC_FLOATS*4 + (size_t)NG*CNT_STRIDE*4, stream);
    pack_weights<<<320, 256, 0, stream>>>(W1_mu, W2_mu, W1_sg, W2_sg, wsh);
    nsde_regw<<<NG*GB, NT, 0, stream>>>(y0, controls, noise,
                                        b1_mu, b2_mu, b1_sg, b2_sg,
                                        (const _Float16*)wsh,
                                        accbuf, cnt, out);
}